// Round 1
// baseline (7997.107 us; speedup 1.0000x reference)
//
#include <hip/hip_runtime.h>
#include <hip/hip_bf16.h>

#define D_MODEL 2048
#define NH 32
#define HDIM 64
#define KVHEADS 8
#define DKV 512
#define DFF 8192
#define SEQ 1024
#define BATCH 4
#define NTOK 4096
#define VOCAB 32000
#define NLAYER 4

typedef __attribute__((ext_vector_type(8))) short short8;
typedef __attribute__((ext_vector_type(4))) float f32x4;

static __device__ __forceinline__ ushort f2bf(float x){
    union { float f; unsigned u; } c; c.f = x;
    unsigned r = (c.u + 0x7FFFu + ((c.u >> 16) & 1u)) >> 16;
    return (ushort)r;
}
static __device__ __forceinline__ float bf2f(ushort h){
    union { float f; unsigned u; } c; c.u = ((unsigned)h) << 16; return c.f;
}

// ---------------- embedding gather ----------------
__global__ __launch_bounds__(256)
void gather_kernel(const int* __restrict__ tok, const float* __restrict__ embed,
                   float* __restrict__ X)
{
    int row = blockIdx.x;
    int id = tok[row];
    const float4* s = (const float4*)(embed + (size_t)id * D_MODEL);
    float4* d = (float4*)(X + (size_t)row * D_MODEL);
    d[threadIdx.x]       = s[threadIdx.x];
    d[threadIdx.x + 256] = s[threadIdx.x + 256];
}

// ---------------- rmsnorm (one block per row) ----------------
__global__ __launch_bounds__(256)
void rmsnorm_kernel(const float* __restrict__ X, const float* __restrict__ gamma,
                    float* __restrict__ O)
{
    int row = blockIdx.x;
    const float* x = X + (size_t)row * D_MODEL;
    float* o = O + (size_t)row * D_MODEL;
    int t = threadIdx.x;
    float4 v[2];
    float ss = 0.f;
#pragma unroll
    for (int i = 0; i < 2; i++){
        v[i] = *(const float4*)&x[(t + i*256)*4];
        ss += v[i].x*v[i].x + v[i].y*v[i].y + v[i].z*v[i].z + v[i].w*v[i].w;
    }
    for (int off = 32; off; off >>= 1) ss += __shfl_xor(ss, off, 64);
    __shared__ float red[4];
    __shared__ float invs;
    int lane = t & 63, wid = t >> 6;
    if (lane == 0) red[wid] = ss;
    __syncthreads();
    if (t == 0){
        float s = red[0] + red[1] + red[2] + red[3];
        invs = 1.0f / sqrtf(s / (float)D_MODEL + 1e-5f);
    }
    __syncthreads();
    float inv = invs;
#pragma unroll
    for (int i = 0; i < 2; i++){
        float4 g = *(const float4*)&gamma[(t + i*256)*4];
        float4 r;
        r.x = v[i].x * inv * g.x; r.y = v[i].y * inv * g.y;
        r.z = v[i].z * inv * g.z; r.w = v[i].w * inv * g.w;
        *(float4*)&o[(t + i*256)*4] = r;
    }
}

// final norm: only last token of each batch
__global__ __launch_bounds__(256)
void final_norm_kernel(const float* __restrict__ X, const float* __restrict__ gamma,
                       float* __restrict__ XF)
{
    int b = blockIdx.x;
    const float* x = X + ((size_t)b * SEQ + SEQ - 1) * D_MODEL;
    float* o = XF + (size_t)b * D_MODEL;
    int t = threadIdx.x;
    float4 v[2];
    float ss = 0.f;
#pragma unroll
    for (int i = 0; i < 2; i++){
        v[i] = *(const float4*)&x[(t + i*256)*4];
        ss += v[i].x*v[i].x + v[i].y*v[i].y + v[i].z*v[i].z + v[i].w*v[i].w;
    }
    for (int off = 32; off; off >>= 1) ss += __shfl_xor(ss, off, 64);
    __shared__ float red[4];
    __shared__ float invs;
    int lane = t & 63, wid = t >> 6;
    if (lane == 0) red[wid] = ss;
    __syncthreads();
    if (t == 0){
        float s = red[0] + red[1] + red[2] + red[3];
        invs = 1.0f / sqrtf(s / (float)D_MODEL + 1e-5f);
    }
    __syncthreads();
    float inv = invs;
#pragma unroll
    for (int i = 0; i < 2; i++){
        float4 g = *(const float4*)&gamma[(t + i*256)*4];
        float4 r;
        r.x = v[i].x * inv * g.x; r.y = v[i].y * inv * g.y;
        r.z = v[i].z * inv * g.z; r.w = v[i].w * inv * g.w;
        *(float4*)&o[(t + i*256)*4] = r;
    }
}

// ---------------- RoPE (in place, split-half) ----------------
__global__ __launch_bounds__(256)
void rope_kernel(float* __restrict__ buf, int nh, int total)
{
    int idx = blockIdx.x * 256 + threadIdx.x;
    if (idx >= total) return;
    int d = idx & 31;
    int head = (idx >> 5) % nh;
    int row = idx / (nh * 32);
    int pos = row & (SEQ - 1);
    float inv = powf(500000.0f, -(float)d * (1.0f / 32.0f));
    float ang = (float)pos * inv;
    float s, c;
    sincosf(ang, &s, &c);
    float* p = buf + (size_t)row * (nh * HDIM) + head * HDIM + d;
    float x1 = p[0], x2 = p[32];
    p[0]  = x1 * c - x2 * s;
    p[32] = x1 * s + x2 * c;
}

// ---------------- quantized GEMM:  C = A[M,K] @ (Wint[N,K] * scale[N])^T ----------------
// hi/lo bf16 split of A keeps fp32-level accuracy. EPI: 0=store 1=add 2=silu(y)*C->C
template<int EPI>
__global__ __launch_bounds__(256)
void gemm_qlin(const float* __restrict__ A, const int* __restrict__ W,
               const float* __restrict__ scale, float* __restrict__ C,
               int M, int N, int K)
{
    __shared__ ushort lds[3 * 128 * 40];
    ushort* Ahi = lds;
    ushort* Alo = lds + 128 * 40;
    ushort* Wb  = lds + 2 * 128 * 40;

    const int t = threadIdx.x;
    const int lane = t & 63, wid = t >> 6;
    const int m0 = blockIdx.x * 128, n0 = blockIdx.y * 128;
    const int wm = (wid >> 1) * 64, wn = (wid & 1) * 64;
    const int ln15 = lane & 15, lq = lane >> 4;

    f32x4 acc[4][4];
#pragma unroll
    for (int i = 0; i < 4; i++)
#pragma unroll
        for (int j = 0; j < 4; j++) acc[i][j] = (f32x4){0.f, 0.f, 0.f, 0.f};

    for (int kk = 0; kk < K; kk += 32){
        float4 a4[4]; int4 w4[4];
#pragma unroll
        for (int i = 0; i < 4; i++){
            int f = t + i * 256;
            int row = f >> 3, c = (f & 7) << 2;
            a4[i] = *(const float4*)&A[(size_t)(m0 + row) * K + kk + c];
            w4[i] = *(const int4*)&W[(size_t)(n0 + row) * K + kk + c];
        }
        __syncthreads();
#pragma unroll
        for (int i = 0; i < 4; i++){
            int f = t + i * 256;
            int row = f >> 3, c = (f & 7) << 2;
            float av[4] = {a4[i].x, a4[i].y, a4[i].z, a4[i].w};
            int   wv[4] = {w4[i].x, w4[i].y, w4[i].z, w4[i].w};
            ushort4 h4, l4, b4;
            ushort hh;
            hh = f2bf(av[0]); h4.x = hh; l4.x = f2bf(av[0] - bf2f(hh));
            hh = f2bf(av[1]); h4.y = hh; l4.y = f2bf(av[1] - bf2f(hh));
            hh = f2bf(av[2]); h4.z = hh; l4.z = f2bf(av[2] - bf2f(hh));
            hh = f2bf(av[3]); h4.w = hh; l4.w = f2bf(av[3] - bf2f(hh));
            b4.x = f2bf((float)wv[0]); b4.y = f2bf((float)wv[1]);
            b4.z = f2bf((float)wv[2]); b4.w = f2bf((float)wv[3]);
            *(ushort4*)&Ahi[row * 40 + c] = h4;
            *(ushort4*)&Alo[row * 40 + c] = l4;
            *(ushort4*)&Wb[row * 40 + c]  = b4;
        }
        __syncthreads();

        short8 bfr[4];
#pragma unroll
        for (int nf = 0; nf < 4; nf++)
            bfr[nf] = *(const short8*)&Wb[(wn + nf * 16 + ln15) * 40 + lq * 8];
#pragma unroll
        for (int mf = 0; mf < 4; mf++){
            short8 ah = *(const short8*)&Ahi[(wm + mf * 16 + ln15) * 40 + lq * 8];
            short8 al = *(const short8*)&Alo[(wm + mf * 16 + ln15) * 40 + lq * 8];
#pragma unroll
            for (int nf = 0; nf < 4; nf++){
                acc[mf][nf] = __builtin_amdgcn_mfma_f32_16x16x32_bf16(ah, bfr[nf], acc[mf][nf], 0, 0, 0);
                acc[mf][nf] = __builtin_amdgcn_mfma_f32_16x16x32_bf16(al, bfr[nf], acc[mf][nf], 0, 0, 0);
            }
        }
    }

#pragma unroll
    for (int mf = 0; mf < 4; mf++){
        int row = m0 + wm + mf * 16 + lq * 4;
#pragma unroll
        for (int nf = 0; nf < 4; nf++){
            int col = n0 + wn + nf * 16 + ln15;
            float sc = scale[col];
#pragma unroll
            for (int r = 0; r < 4; r++){
                size_t idx = (size_t)(row + r) * N + col;
                float val = acc[mf][nf][r] * sc;
                if (EPI == 0){
                    C[idx] = val;
                } else if (EPI == 1){
                    C[idx] += val;
                } else {
                    float uv = C[idx];
                    float sig = 1.0f / (1.0f + expf(-val));
                    C[idx] = val * sig * uv;
                }
            }
        }
    }
}

// ---------------- flash attention (causal, GQA 4:1) ----------------
__global__ __launch_bounds__(256)
void attn_kernel(const float* __restrict__ Qb, const float* __restrict__ Kb,
                 const float* __restrict__ Vb, float* __restrict__ Ob)
{
    int bid = blockIdx.x;
    int qt = bid & 7, h = (bid >> 3) & 31, b = bid >> 8;
    int kvh = h >> 2;
    int q0 = qt * 128;
    int t = threadIdx.x, lane = t & 63, wid = t >> 6;
    int ln15 = lane & 15, lq = lane >> 4;

    __shared__ ushort Khi[64 * 72], Klo[64 * 72], Vthi[64 * 72], Vtlo[64 * 72];
    __shared__ ushort Pl[128 * 72];

    // Q fragments (kept in registers, hi/lo split)
    short8 qhi[2][2], qlo[2][2];
    int qrow_g = b * SEQ + q0 + wid * 32;
#pragma unroll
    for (int mf = 0; mf < 2; mf++){
#pragma unroll
        for (int dc = 0; dc < 2; dc++){
            const float* src = Qb + (size_t)(qrow_g + mf * 16 + ln15) * D_MODEL
                               + h * HDIM + dc * 32 + lq * 8;
            float4 v0 = *(const float4*)src;
            float4 v1 = *(const float4*)(src + 4);
            float av[8] = {v0.x, v0.y, v0.z, v0.w, v1.x, v1.y, v1.z, v1.w};
            short8 hh, ll;
#pragma unroll
            for (int e = 0; e < 8; e++){
                ushort hb = f2bf(av[e]);
                hh[e] = (short)hb;
                ll[e] = (short)f2bf(av[e] - bf2f(hb));
            }
            qhi[mf][dc] = hh; qlo[mf][dc] = ll;
        }
    }

    f32x4 outv[2][4];
#pragma unroll
    for (int i = 0; i < 2; i++)
#pragma unroll
        for (int j = 0; j < 4; j++) outv[i][j] = (f32x4){0.f, 0.f, 0.f, 0.f};
    float mrun[2][4], lrun[2][4];
#pragma unroll
    for (int i = 0; i < 2; i++)
#pragma unroll
        for (int r = 0; r < 4; r++){ mrun[i][r] = -1e30f; lrun[i][r] = 0.f; }

    int ntile = (q0 + 128) >> 6;
    for (int kt = 0; kt < ntile; kt++){
        float4 k4[4], v4[4];
#pragma unroll
        for (int i = 0; i < 4; i++){
            int f = t + i * 256;
            int row = f >> 4, c = (f & 15) << 2;
            size_t base = (size_t)(b * SEQ + kt * 64 + row) * DKV + kvh * HDIM + c;
            k4[i] = *(const float4*)&Kb[base];
            v4[i] = *(const float4*)&Vb[base];
        }
        __syncthreads();
#pragma unroll
        for (int i = 0; i < 4; i++){
            int f = t + i * 256;
            int row = f >> 4, c = (f & 15) << 2;
            float kv[4] = {k4[i].x, k4[i].y, k4[i].z, k4[i].w};
            float vv[4] = {v4[i].x, v4[i].y, v4[i].z, v4[i].w};
            ushort4 h4, l4;
            ushort hb;
            hb = f2bf(kv[0]); h4.x = hb; l4.x = f2bf(kv[0] - bf2f(hb));
            hb = f2bf(kv[1]); h4.y = hb; l4.y = f2bf(kv[1] - bf2f(hb));
            hb = f2bf(kv[2]); h4.z = hb; l4.z = f2bf(kv[2] - bf2f(hb));
            hb = f2bf(kv[3]); h4.w = hb; l4.w = f2bf(kv[3] - bf2f(hb));
            *(ushort4*)&Khi[row * 72 + c] = h4;
            *(ushort4*)&Klo[row * 72 + c] = l4;
#pragma unroll
            for (int j = 0; j < 4; j++){
                ushort vh = f2bf(vv[j]);
                Vthi[(c + j) * 72 + row] = vh;
                Vtlo[(c + j) * 72 + row] = f2bf(vv[j] - bf2f(vh));
            }
        }
        __syncthreads();

        // scores + online softmax per mf
#pragma unroll
        for (int mf = 0; mf < 2; mf++){
            f32x4 sa[4];
#pragma unroll
            for (int kvf = 0; kvf < 4; kvf++) sa[kvf] = (f32x4){0.f, 0.f, 0.f, 0.f};
#pragma unroll
            for (int kvf = 0; kvf < 4; kvf++){
#pragma unroll
                for (int dc = 0; dc < 2; dc++){
                    short8 kbh = *(const short8*)&Khi[(kvf * 16 + ln15) * 72 + dc * 32 + lq * 8];
                    short8 kbl = *(const short8*)&Klo[(kvf * 16 + ln15) * 72 + dc * 32 + lq * 8];
                    sa[kvf] = __builtin_amdgcn_mfma_f32_16x16x32_bf16(qhi[mf][dc], kbh, sa[kvf], 0, 0, 0);
                    sa[kvf] = __builtin_amdgcn_mfma_f32_16x16x32_bf16(qlo[mf][dc], kbh, sa[kvf], 0, 0, 0);
                    sa[kvf] = __builtin_amdgcn_mfma_f32_16x16x32_bf16(qhi[mf][dc], kbl, sa[kvf], 0, 0, 0);
                }
            }
            int qbase = q0 + wid * 32 + mf * 16 + lq * 4;
            float rowmax[4] = {-1e30f, -1e30f, -1e30f, -1e30f};
#pragma unroll
            for (int kvf = 0; kvf < 4; kvf++){
                int kva = kt * 64 + kvf * 16 + ln15;
#pragma unroll
                for (int r = 0; r < 4; r++){
                    float sv = sa[kvf][r] * 0.125f;
                    if (kva > qbase + r) sv = -1e9f;
                    sa[kvf][r] = sv;
                    rowmax[r] = fmaxf(rowmax[r], sv);
                }
            }
#pragma unroll
            for (int r = 0; r < 4; r++){
                rowmax[r] = fmaxf(rowmax[r], __shfl_xor(rowmax[r], 1, 64));
                rowmax[r] = fmaxf(rowmax[r], __shfl_xor(rowmax[r], 2, 64));
                rowmax[r] = fmaxf(rowmax[r], __shfl_xor(rowmax[r], 4, 64));
                rowmax[r] = fmaxf(rowmax[r], __shfl_xor(rowmax[r], 8, 64));
            }
            float scl[4], rsum[4];
#pragma unroll
            for (int r = 0; r < 4; r++){
                float mo = mrun[mf][r];
                float mn = fmaxf(mo, rowmax[r]);
                scl[r] = expf(mo - mn);
                mrun[mf][r] = mn;
                rsum[r] = 0.f;
            }
#pragma unroll
            for (int kvf = 0; kvf < 4; kvf++){
#pragma unroll
                for (int r = 0; r < 4; r++){
                    float p = expf(sa[kvf][r] - mrun[mf][r]);
                    sa[kvf][r] = p;
                    rsum[r] += p;
                }
            }
#pragma unroll
            for (int r = 0; r < 4; r++){
                rsum[r] += __shfl_xor(rsum[r], 1, 64);
                rsum[r] += __shfl_xor(rsum[r], 2, 64);
                rsum[r] += __shfl_xor(rsum[r], 4, 64);
                rsum[r] += __shfl_xor(rsum[r], 8, 64);
                lrun[mf][r] = lrun[mf][r] * scl[r] + rsum[r];
            }
#pragma unroll
            for (int dfr = 0; dfr < 4; dfr++)
#pragma unroll
                for (int r = 0; r < 4; r++) outv[mf][dfr][r] *= scl[r];
#pragma unroll
            for (int kvf = 0; kvf < 4; kvf++)
#pragma unroll
                for (int r = 0; r < 4; r++)
                    Pl[(wid * 32 + mf * 16 + lq * 4 + r) * 72 + kvf * 16 + ln15] = f2bf(sa[kvf][r]);
        }

        // PV
#pragma unroll
        for (int mf = 0; mf < 2; mf++){
#pragma unroll
            for (int kc = 0; kc < 2; kc++){
                short8 pa = *(const short8*)&Pl[(wid * 32 + mf * 16 + ln15) * 72 + kc * 32 + lq * 8];
#pragma unroll
                for (int dfr = 0; dfr < 4; dfr++){
                    short8 vbh = *(const short8*)&Vthi[(dfr * 16 + ln15) * 72 + kc * 32 + lq * 8];
                    short8 vbl = *(const short8*)&Vtlo[(dfr * 16 + ln15) * 72 + kc * 32 + lq * 8];
                    outv[mf][dfr] = __builtin_amdgcn_mfma_f32_16x16x32_bf16(pa, vbh, outv[mf][dfr], 0, 0, 0);
                    outv[mf][dfr] = __builtin_amdgcn_mfma_f32_16x16x32_bf16(pa, vbl, outv[mf][dfr], 0, 0, 0);
                }
            }
        }
    }

#pragma unroll
    for (int mf = 0; mf < 2; mf++){
#pragma unroll
        for (int dfr = 0; dfr < 4; dfr++){
#pragma unroll
            for (int r = 0; r < 4; r++){
                float val = outv[mf][dfr][r] / lrun[mf][r];
                size_t row = (size_t)(b * SEQ + q0 + wid * 32 + mf * 16 + lq * 4 + r);
                Ob[row * D_MODEL + h * HDIM + dfr * 16 + ln15] = val;
            }
        }
    }
}

// ---------------- LM head: out[b][v] = xf[b] . embed[v] ----------------
__global__ __launch_bounds__(256)
void lmhead_kernel(const float* __restrict__ XF, const float* __restrict__ embed,
                   float* __restrict__ out)
{
    __shared__ float xl[4 * D_MODEL];
    int t = threadIdx.x;
#pragma unroll
    for (int i = 0; i < 8; i++){
        int f = t + i * 256;
        ((float4*)xl)[f] = ((const float4*)XF)[f];
    }
    __syncthreads();
    int lane = t & 63, wid = t >> 6;
    for (int rr = 0; rr < 16; rr++){
        int vrow = blockIdx.x * 64 + wid * 16 + rr;
        const float4* er = (const float4*)(embed + (size_t)vrow * D_MODEL);
        float acc[4] = {0.f, 0.f, 0.f, 0.f};
        for (int j = 0; j < 8; j++){
            float4 e = er[lane + 64 * j];
#pragma unroll
            for (int b = 0; b < 4; b++){
                float4 xv = ((float4*)xl)[b * 512 + lane + 64 * j];
                acc[b] += e.x * xv.x + e.y * xv.y + e.z * xv.z + e.w * xv.w;
            }
        }
#pragma unroll
        for (int b = 0; b < 4; b++)
            for (int off = 32; off; off >>= 1) acc[b] += __shfl_xor(acc[b], off, 64);
        if (lane == 0){
#pragma unroll
            for (int b = 0; b < 4; b++)
                out[(size_t)b * VOCAB + vrow] = acc[b];
        }
    }
}

extern "C" void kernel_launch(void* const* d_in, const int* in_sizes, int n_in,
                              void* d_out, int out_size, void* d_ws, size_t ws_size,
                              hipStream_t stream)
{
    const int*   tok   = (const int*)d_in[0];
    const float* embed = (const float*)d_in[1];
    const float* g_attn = (const float*)d_in[2];
    const float* g_mlp  = (const float*)d_in[3];
    const float* g_fin  = (const float*)d_in[4];
    const int*   wq = (const int*)d_in[5];  const float* sq = (const float*)d_in[6];
    const int*   wk = (const int*)d_in[7];  const float* sk = (const float*)d_in[8];
    const int*   wv = (const int*)d_in[9];  const float* sv = (const float*)d_in[10];
    const int*   wo = (const int*)d_in[11]; const float* so = (const float*)d_in[12];
    const int*   wg = (const int*)d_in[13]; const float* sg = (const float*)d_in[14];
    const int*   wu = (const int*)d_in[15]; const float* su = (const float*)d_in[16];
    const int*   wd = (const int*)d_in[17]; const float* sd = (const float*)d_in[18];
    float* out = (float*)d_out;

    float* ws = (float*)d_ws;
    float* X  = ws;
    float* Hb = X  + (size_t)NTOK * D_MODEL;
    float* Qb = Hb + (size_t)NTOK * D_MODEL;
    float* Ab = Qb + (size_t)NTOK * D_MODEL;
    float* Kb = Ab + (size_t)NTOK * D_MODEL;
    float* Vb = Kb + (size_t)NTOK * DKV;
    float* Ub = Vb + (size_t)NTOK * DKV;
    float* XF = Ub + (size_t)NTOK * DFF;

    gather_kernel<<<NTOK, 256, 0, stream>>>(tok, embed, X);

    for (int l = 0; l < NLAYER; l++){
        rmsnorm_kernel<<<NTOK, 256, 0, stream>>>(X, g_attn + (size_t)l * D_MODEL, Hb);
        gemm_qlin<0><<<dim3(32, 16), 256, 0, stream>>>(
            Hb, wq + (size_t)l * D_MODEL * D_MODEL, sq + (size_t)l * D_MODEL, Qb,
            NTOK, D_MODEL, D_MODEL);
        gemm_qlin<0><<<dim3(32, 4), 256, 0, stream>>>(
            Hb, wk + (size_t)l * DKV * D_MODEL, sk + (size_t)l * DKV, Kb,
            NTOK, DKV, D_MODEL);
        gemm_qlin<0><<<dim3(32, 4), 256, 0, stream>>>(
            Hb, wv + (size_t)l * DKV * D_MODEL, sv + (size_t)l * DKV, Vb,
            NTOK, DKV, D_MODEL);
        {
            int totq = NTOK * NH * 32;
            rope_kernel<<<(totq + 255) / 256, 256, 0, stream>>>(Qb, NH, totq);
            int totk = NTOK * KVHEADS * 32;
            rope_kernel<<<(totk + 255) / 256, 256, 0, stream>>>(Kb, KVHEADS, totk);
        }
        attn_kernel<<<1024, 256, 0, stream>>>(Qb, Kb, Vb, Ab);
        gemm_qlin<1><<<dim3(32, 16), 256, 0, stream>>>(
            Ab, wo + (size_t)l * D_MODEL * D_MODEL, so + (size_t)l * D_MODEL, X,
            NTOK, D_MODEL, D_MODEL);
        rmsnorm_kernel<<<NTOK, 256, 0, stream>>>(X, g_mlp + (size_t)l * D_MODEL, Hb);
        gemm_qlin<0><<<dim3(32, 64), 256, 0, stream>>>(
            Hb, wu + (size_t)l * DFF * D_MODEL, su + (size_t)l * DFF, Ub,
            NTOK, DFF, D_MODEL);
        gemm_qlin<2><<<dim3(32, 64), 256, 0, stream>>>(
            Hb, wg + (size_t)l * DFF * D_MODEL, sg + (size_t)l * DFF, Ub,
            NTOK, DFF, D_MODEL);
        gemm_qlin<1><<<dim3(32, 16), 256, 0, stream>>>(
            Ub, wd + (size_t)l * D_MODEL * DFF, sd + (size_t)l * D_MODEL, X,
            NTOK, D_MODEL, DFF);
    }

    final_norm_kernel<<<BATCH, 256, 0, stream>>>(X, g_fin, XF);
    lmhead_kernel<<<VOCAB / 64, 256, 0, stream>>>(XF, embed, out);
}

// Round 2
// 4668.146 us; speedup vs baseline: 1.7131x; 1.7131x over previous
//
#include <hip/hip_runtime.h>
#include <hip/hip_bf16.h>

#define D_MODEL 2048
#define NH 32
#define HDIM 64
#define KVHEADS 8
#define DKV 512
#define DFF 8192
#define SEQ 1024
#define BATCH 4
#define NTOK 4096
#define VOCAB 32000
#define NLAYER 4

typedef __attribute__((ext_vector_type(8))) _Float16 f16x8;
typedef __attribute__((ext_vector_type(4))) _Float16 f16x4;
typedef __attribute__((ext_vector_type(4))) float f32x4;

static __device__ __forceinline__ void gload16(const void* g, void* l){
    __builtin_amdgcn_global_load_lds(
        (const __attribute__((address_space(1))) unsigned int*)g,
        (__attribute__((address_space(3))) unsigned int*)l, 16, 0, 0);
}

// ---------------- embedding gather ----------------
__global__ __launch_bounds__(256)
void gather_kernel(const int* __restrict__ tok, const float* __restrict__ embed,
                   float* __restrict__ X)
{
    int row = blockIdx.x;
    int id = tok[row];
    const float4* s = (const float4*)(embed + (size_t)id * D_MODEL);
    float4* d = (float4*)(X + (size_t)row * D_MODEL);
    d[threadIdx.x]       = s[threadIdx.x];
    d[threadIdx.x + 256] = s[threadIdx.x + 256];
}

// ---------------- weight convert: int32 -> fp16 ----------------
__global__ __launch_bounds__(256)
void wconv_kernel(const int* __restrict__ W, _Float16* __restrict__ O, int n4)
{
    int i = blockIdx.x * 256 + threadIdx.x;
    if (i >= n4) return;
    int4 w = ((const int4*)W)[i];
    f16x4 o;
    o.x = (_Float16)(float)w.x; o.y = (_Float16)(float)w.y;
    o.z = (_Float16)(float)w.z; o.w = (_Float16)(float)w.w;
    ((f16x4*)O)[i] = o;
}

// ---------------- rmsnorm (fp32 in, fp16 out) ----------------
__global__ __launch_bounds__(256)
void rmsnorm_kernel(const float* __restrict__ X, const float* __restrict__ gamma,
                    _Float16* __restrict__ O)
{
    int row = blockIdx.x;
    const float* x = X + (size_t)row * D_MODEL;
    _Float16* o = O + (size_t)row * D_MODEL;
    int t = threadIdx.x;
    float4 v[2];
    float ss = 0.f;
#pragma unroll
    for (int i = 0; i < 2; i++){
        v[i] = *(const float4*)&x[(t + i*256)*4];
        ss += v[i].x*v[i].x + v[i].y*v[i].y + v[i].z*v[i].z + v[i].w*v[i].w;
    }
    for (int off = 32; off; off >>= 1) ss += __shfl_xor(ss, off, 64);
    __shared__ float red[4];
    __shared__ float invs;
    int lane = t & 63, wid = t >> 6;
    if (lane == 0) red[wid] = ss;
    __syncthreads();
    if (t == 0){
        float s = red[0] + red[1] + red[2] + red[3];
        invs = 1.0f / sqrtf(s / (float)D_MODEL + 1e-5f);
    }
    __syncthreads();
    float inv = invs;
#pragma unroll
    for (int i = 0; i < 2; i++){
        float4 g = *(const float4*)&gamma[(t + i*256)*4];
        f16x4 r;
        r.x = (_Float16)(v[i].x * inv * g.x); r.y = (_Float16)(v[i].y * inv * g.y);
        r.z = (_Float16)(v[i].z * inv * g.z); r.w = (_Float16)(v[i].w * inv * g.w);
        *(f16x4*)&o[(t + i*256)*4] = r;
    }
}

// final norm (fp32 out), last token per batch
__global__ __launch_bounds__(256)
void final_norm_kernel(const float* __restrict__ X, const float* __restrict__ gamma,
                       float* __restrict__ XF)
{
    int b = blockIdx.x;
    const float* x = X + ((size_t)b * SEQ + SEQ - 1) * D_MODEL;
    float* o = XF + (size_t)b * D_MODEL;
    int t = threadIdx.x;
    float4 v[2];
    float ss = 0.f;
#pragma unroll
    for (int i = 0; i < 2; i++){
        v[i] = *(const float4*)&x[(t + i*256)*4];
        ss += v[i].x*v[i].x + v[i].y*v[i].y + v[i].z*v[i].z + v[i].w*v[i].w;
    }
    for (int off = 32; off; off >>= 1) ss += __shfl_xor(ss, off, 64);
    __shared__ float red[4];
    __shared__ float invs;
    int lane = t & 63, wid = t >> 6;
    if (lane == 0) red[wid] = ss;
    __syncthreads();
    if (t == 0){
        float s = red[0] + red[1] + red[2] + red[3];
        invs = 1.0f / sqrtf(s / (float)D_MODEL + 1e-5f);
    }
    __syncthreads();
    float inv = invs;
#pragma unroll
    for (int i = 0; i < 2; i++){
        float4 g = *(const float4*)&gamma[(t + i*256)*4];
        float4 r;
        r.x = v[i].x * inv * g.x; r.y = v[i].y * inv * g.y;
        r.z = v[i].z * inv * g.z; r.w = v[i].w * inv * g.w;
        *(float4*)&o[(t + i*256)*4] = r;
    }
}

// ---------------- RoPE (fp16 in place, split-half) ----------------
__global__ __launch_bounds__(256)
void rope_f16_kernel(_Float16* __restrict__ buf, int nh, int total)
{
    int idx = blockIdx.x * 256 + threadIdx.x;
    if (idx >= total) return;
    int d = idx & 31;
    int head = (idx >> 5) % nh;
    int row = idx / (nh * 32);
    int pos = row & (SEQ - 1);
    float inv = powf(500000.0f, -(float)d * (1.0f / 32.0f));
    float ang = (float)pos * inv;
    float s, c;
    sincosf(ang, &s, &c);
    _Float16* p = buf + (size_t)row * (nh * HDIM) + head * HDIM + d;
    float x1 = (float)p[0], x2 = (float)p[32];
    p[0]  = (_Float16)(x1 * c - x2 * s);
    p[32] = (_Float16)(x1 * s + x2 * c);
}

// ---------------- fp16 GEMM:  C = A[M,K] @ W[N,K]^T * scale[N] ----------------
// m97 structure: global_load_lds staging, chunk-XOR swizzle, 16x16x32 f16 MFMA.
// EPI: 0 = store fp16; 1 = add into fp32; 2 = silu(y)*C -> C (fp16 in-place)
template<int EPI>
__global__ __launch_bounds__(256)
void gemm_f16(const _Float16* __restrict__ A, const _Float16* __restrict__ W,
              const float* __restrict__ scale, void* __restrict__ Cv,
              int M, int N, int K)
{
    __shared__ __align__(16) _Float16 Asm[128 * 32];
    __shared__ __align__(16) _Float16 Wsm[128 * 32];

    const int t = threadIdx.x;
    const int lane = t & 63, wid = t >> 6;
    const int m0 = blockIdx.x * 128, n0 = blockIdx.y * 128;
    const int wm = (wid >> 1) * 64, wn = (wid & 1) * 64;
    const int ln15 = lane & 15, lq = lane >> 4;
    const int ca = (ln15 >> 1) & 3;          // read-side swizzle constant

    // staging: chunk index f in [0,512); row=f>>2, slot=f&3; source chunk slot^((row>>1)&3)
    int f0 = t, f1 = 256 + t;
    int r0 = f0 >> 2, c0 = (f0 & 3) ^ ((f0 >> 3) & 3);
    int r1 = f1 >> 2, c1 = (f1 & 3) ^ ((f1 >> 3) & 3);
    _Float16* dstA0 = &Asm[(size_t)(wid * 64) * 8];
    _Float16* dstA1 = &Asm[(size_t)(256 + wid * 64) * 8];
    _Float16* dstW0 = &Wsm[(size_t)(wid * 64) * 8];
    _Float16* dstW1 = &Wsm[(size_t)(256 + wid * 64) * 8];
    const _Float16* Abase0 = A + (size_t)(m0 + r0) * K + c0 * 8;
    const _Float16* Abase1 = A + (size_t)(m0 + r1) * K + c1 * 8;
    const _Float16* Wbase0 = W + (size_t)(n0 + r0) * K + c0 * 8;
    const _Float16* Wbase1 = W + (size_t)(n0 + r1) * K + c1 * 8;

    f32x4 acc[4][4];
#pragma unroll
    for (int i = 0; i < 4; i++)
#pragma unroll
        for (int j = 0; j < 4; j++) acc[i][j] = (f32x4){0.f, 0.f, 0.f, 0.f};

    for (int kk = 0; kk < K; kk += 32){
        gload16(Abase0 + kk, dstA0);
        gload16(Abase1 + kk, dstA1);
        gload16(Wbase0 + kk, dstW0);
        gload16(Wbase1 + kk, dstW1);
        __syncthreads();

        f16x8 afr[4], wfr[4];
#pragma unroll
        for (int nf = 0; nf < 4; nf++)
            wfr[nf] = *(const f16x8*)&Wsm[(wn + nf * 16 + ln15) * 32 + (lq ^ ca) * 8];
#pragma unroll
        for (int mf = 0; mf < 4; mf++)
            afr[mf] = *(const f16x8*)&Asm[(wm + mf * 16 + ln15) * 32 + (lq ^ ca) * 8];
#pragma unroll
        for (int mf = 0; mf < 4; mf++)
#pragma unroll
            for (int nf = 0; nf < 4; nf++)
                acc[mf][nf] = __builtin_amdgcn_mfma_f32_16x16x32_f16(afr[mf], wfr[nf], acc[mf][nf], 0, 0, 0);
        __syncthreads();
    }

#pragma unroll
    for (int mf = 0; mf < 4; mf++){
        int row = m0 + wm + mf * 16 + lq * 4;
#pragma unroll
        for (int nf = 0; nf < 4; nf++){
            int col = n0 + wn + nf * 16 + ln15;
            float sc = scale[col];
#pragma unroll
            for (int r = 0; r < 4; r++){
                size_t idx = (size_t)(row + r) * N + col;
                float val = acc[mf][nf][r] * sc;
                if (EPI == 0){
                    ((_Float16*)Cv)[idx] = (_Float16)val;
                } else if (EPI == 1){
                    ((float*)Cv)[idx] += val;
                } else {
                    _Float16* C = (_Float16*)Cv;
                    float uv = (float)C[idx];
                    float sig = 1.0f / (1.0f + expf(-val));
                    C[idx] = (_Float16)(val * sig * uv);
                }
            }
        }
    }
}

// ---------------- flash attention (causal, GQA 4:1, fp16) ----------------
__global__ __launch_bounds__(256)
void attn_kernel(const _Float16* __restrict__ Qb, const _Float16* __restrict__ Kb,
                 const _Float16* __restrict__ Vb, _Float16* __restrict__ Ob)
{
    int bid = blockIdx.x;
    int qt = bid & 7, h = (bid >> 3) & 31, b = bid >> 8;
    int kvh = h >> 2;
    int q0 = qt * 128;
    int t = threadIdx.x, lane = t & 63, wid = t >> 6;
    int ln15 = lane & 15, lq = lane >> 4;

    __shared__ __align__(16) _Float16 Ksm[64 * 72];
    __shared__ __align__(16) _Float16 Vt[64 * 72];
    __shared__ __align__(16) _Float16 Pl[128 * 72];

    // Q fragments in registers
    f16x8 qf[2][2];
    int qrow_g = b * SEQ + q0 + wid * 32;
#pragma unroll
    for (int mf = 0; mf < 2; mf++)
#pragma unroll
        for (int dc = 0; dc < 2; dc++)
            qf[mf][dc] = *(const f16x8*)(Qb + (size_t)(qrow_g + mf * 16 + ln15) * D_MODEL
                                         + h * HDIM + dc * 32 + lq * 8);

    f32x4 outv[2][4];
#pragma unroll
    for (int i = 0; i < 2; i++)
#pragma unroll
        for (int j = 0; j < 4; j++) outv[i][j] = (f32x4){0.f, 0.f, 0.f, 0.f};
    float mrun[2][4], lrun[2][4];
#pragma unroll
    for (int i = 0; i < 2; i++)
#pragma unroll
        for (int r = 0; r < 4; r++){ mrun[i][r] = -1e30f; lrun[i][r] = 0.f; }

    int ntile = (q0 + 128) >> 6;
    for (int kt = 0; kt < ntile; kt++){
        f16x8 k8[2], v8[2];
#pragma unroll
        for (int i = 0; i < 2; i++){
            int f = t + i * 256;
            int row = f >> 3, c8 = f & 7;
            size_t base = (size_t)(b * SEQ + kt * 64 + row) * DKV + kvh * HDIM + c8 * 8;
            k8[i] = *(const f16x8*)&Kb[base];
            v8[i] = *(const f16x8*)&Vb[base];
        }
        __syncthreads();
#pragma unroll
        for (int i = 0; i < 2; i++){
            int f = t + i * 256;
            int row = f >> 3, c8 = f & 7;
            *(f16x8*)&Ksm[row * 72 + c8 * 8] = k8[i];
#pragma unroll
            for (int j = 0; j < 8; j++)
                Vt[(c8 * 8 + j) * 72 + row] = v8[i][j];
        }
        __syncthreads();

#pragma unroll
        for (int mf = 0; mf < 2; mf++){
            f32x4 sa[4];
#pragma unroll
            for (int kvf = 0; kvf < 4; kvf++) sa[kvf] = (f32x4){0.f, 0.f, 0.f, 0.f};
#pragma unroll
            for (int kvf = 0; kvf < 4; kvf++)
#pragma unroll
                for (int dc = 0; dc < 2; dc++){
                    f16x8 kb = *(const f16x8*)&Ksm[(kvf * 16 + ln15) * 72 + dc * 32 + lq * 8];
                    sa[kvf] = __builtin_amdgcn_mfma_f32_16x16x32_f16(qf[mf][dc], kb, sa[kvf], 0, 0, 0);
                }
            int qbase = q0 + wid * 32 + mf * 16 + lq * 4;
            float rowmax[4] = {-1e30f, -1e30f, -1e30f, -1e30f};
#pragma unroll
            for (int kvf = 0; kvf < 4; kvf++){
                int kva = kt * 64 + kvf * 16 + ln15;
#pragma unroll
                for (int r = 0; r < 4; r++){
                    float sv = sa[kvf][r] * 0.125f;
                    if (kva > qbase + r) sv = -1e9f;
                    sa[kvf][r] = sv;
                    rowmax[r] = fmaxf(rowmax[r], sv);
                }
            }
#pragma unroll
            for (int r = 0; r < 4; r++){
                rowmax[r] = fmaxf(rowmax[r], __shfl_xor(rowmax[r], 1, 64));
                rowmax[r] = fmaxf(rowmax[r], __shfl_xor(rowmax[r], 2, 64));
                rowmax[r] = fmaxf(rowmax[r], __shfl_xor(rowmax[r], 4, 64));
                rowmax[r] = fmaxf(rowmax[r], __shfl_xor(rowmax[r], 8, 64));
            }
            float scl[4], rsum[4];
#pragma unroll
            for (int r = 0; r < 4; r++){
                float mo = mrun[mf][r];
                float mn = fmaxf(mo, rowmax[r]);
                scl[r] = expf(mo - mn);
                mrun[mf][r] = mn;
                rsum[r] = 0.f;
            }
#pragma unroll
            for (int kvf = 0; kvf < 4; kvf++)
#pragma unroll
                for (int r = 0; r < 4; r++){
                    float p = expf(sa[kvf][r] - mrun[mf][r]);
                    sa[kvf][r] = p;
                    rsum[r] += p;
                }
#pragma unroll
            for (int r = 0; r < 4; r++){
                rsum[r] += __shfl_xor(rsum[r], 1, 64);
                rsum[r] += __shfl_xor(rsum[r], 2, 64);
                rsum[r] += __shfl_xor(rsum[r], 4, 64);
                rsum[r] += __shfl_xor(rsum[r], 8, 64);
                lrun[mf][r] = lrun[mf][r] * scl[r] + rsum[r];
            }
#pragma unroll
            for (int dfr = 0; dfr < 4; dfr++)
#pragma unroll
                for (int r = 0; r < 4; r++) outv[mf][dfr][r] *= scl[r];
#pragma unroll
            for (int kvf = 0; kvf < 4; kvf++)
#pragma unroll
                for (int r = 0; r < 4; r++)
                    Pl[(wid * 32 + mf * 16 + lq * 4 + r) * 72 + kvf * 16 + ln15] = (_Float16)sa[kvf][r];
        }
        __syncthreads();

#pragma unroll
        for (int mf = 0; mf < 2; mf++)
#pragma unroll
            for (int kc = 0; kc < 2; kc++){
                f16x8 pa = *(const f16x8*)&Pl[(wid * 32 + mf * 16 + ln15) * 72 + kc * 32 + lq * 8];
#pragma unroll
                for (int dfr = 0; dfr < 4; dfr++){
                    f16x8 vb = *(const f16x8*)&Vt[(dfr * 16 + ln15) * 72 + kc * 32 + lq * 8];
                    outv[mf][dfr] = __builtin_amdgcn_mfma_f32_16x16x32_f16(pa, vb, outv[mf][dfr], 0, 0, 0);
                }
            }
    }

#pragma unroll
    for (int mf = 0; mf < 2; mf++)
#pragma unroll
        for (int dfr = 0; dfr < 4; dfr++)
#pragma unroll
            for (int r = 0; r < 4; r++){
                float val = outv[mf][dfr][r] / lrun[mf][r];
                size_t row = (size_t)(b * SEQ + q0 + wid * 32 + mf * 16 + lq * 4 + r);
                Ob[row * D_MODEL + h * HDIM + dfr * 16 + ln15] = (_Float16)val;
            }
}

// ---------------- LM head: out[b][v] = xf[b] . embed[v] ----------------
__global__ __launch_bounds__(256)
void lmhead_kernel(const float* __restrict__ XF, const float* __restrict__ embed,
                   float* __restrict__ out)
{
    __shared__ float xl[4 * D_MODEL];
    int t = threadIdx.x;
#pragma unroll
    for (int i = 0; i < 8; i++){
        int f = t + i * 256;
        ((float4*)xl)[f] = ((const float4*)XF)[f];
    }
    __syncthreads();
    int lane = t & 63, wid = t >> 6;
    for (int rr = 0; rr < 16; rr++){
        int vrow = blockIdx.x * 64 + wid * 16 + rr;
        const float4* er = (const float4*)(embed + (size_t)vrow * D_MODEL);
        float acc[4] = {0.f, 0.f, 0.f, 0.f};
        for (int j = 0; j < 8; j++){
            float4 e = er[lane + 64 * j];
#pragma unroll
            for (int b = 0; b < 4; b++){
                float4 xv = ((float4*)xl)[b * 512 + lane + 64 * j];
                acc[b] += e.x * xv.x + e.y * xv.y + e.z * xv.z + e.w * xv.w;
            }
        }
#pragma unroll
        for (int b = 0; b < 4; b++)
            for (int off = 32; off; off >>= 1) acc[b] += __shfl_xor(acc[b], off, 64);
        if (lane == 0){
#pragma unroll
            for (int b = 0; b < 4; b++)
                out[(size_t)b * VOCAB + vrow] = acc[b];
        }
    }
}

extern "C" void kernel_launch(void* const* d_in, const int* in_sizes, int n_in,
                              void* d_out, int out_size, void* d_ws, size_t ws_size,
                              hipStream_t stream)
{
    const int*   tok   = (const int*)d_in[0];
    const float* embed = (const float*)d_in[1];
    const float* g_attn = (const float*)d_in[2];
    const float* g_mlp  = (const float*)d_in[3];
    const float* g_fin  = (const float*)d_in[4];
    const int*   wq = (const int*)d_in[5];  const float* sq = (const float*)d_in[6];
    const int*   wk = (const int*)d_in[7];  const float* sk = (const float*)d_in[8];
    const int*   wv = (const int*)d_in[9];  const float* sv = (const float*)d_in[10];
    const int*   wo = (const int*)d_in[11]; const float* so = (const float*)d_in[12];
    const int*   wg = (const int*)d_in[13]; const float* sg = (const float*)d_in[14];
    const int*   wu = (const int*)d_in[15]; const float* su = (const float*)d_in[16];
    const int*   wd = (const int*)d_in[17]; const float* sd = (const float*)d_in[18];
    float* out = (float*)d_out;

    // workspace layout (~281 MB, same footprint class as round-0)
    char* p = (char*)d_ws;
    _Float16* Wf = (_Float16*)p;  p += (size_t)60817408 * 2;   // per-layer fp16 weights
    float*    X  = (float*)p;     p += (size_t)NTOK * D_MODEL * 4;
    _Float16* Hb = (_Float16*)p;  p += (size_t)NTOK * D_MODEL * 2;
    _Float16* Qb = (_Float16*)p;  p += (size_t)NTOK * D_MODEL * 2;
    _Float16* Kb = (_Float16*)p;  p += (size_t)NTOK * DKV * 2;
    _Float16* Vb = (_Float16*)p;  p += (size_t)NTOK * DKV * 2;
    _Float16* Ab = (_Float16*)p;  p += (size_t)NTOK * D_MODEL * 2;
    _Float16* Ub = (_Float16*)p;  p += (size_t)NTOK * DFF * 2;
    float*    XF = (float*)p;     p += (size_t)BATCH * D_MODEL * 4;

    // per-layer fp16 weight sub-buffers
    _Float16* wqf = Wf;
    _Float16* wkf = wqf + (size_t)D_MODEL * D_MODEL;
    _Float16* wvf = wkf + (size_t)DKV * D_MODEL;
    _Float16* wof = wvf + (size_t)DKV * D_MODEL;
    _Float16* wgf = wof + (size_t)D_MODEL * D_MODEL;
    _Float16* wuf = wgf + (size_t)DFF * D_MODEL;
    _Float16* wdf = wuf + (size_t)DFF * D_MODEL;

    gather_kernel<<<NTOK, 256, 0, stream>>>(tok, embed, X);

    for (int l = 0; l < NLAYER; l++){
        // convert this layer's weights to fp16
        {
            const int nDD = D_MODEL * D_MODEL / 4, nKD = DKV * D_MODEL / 4, nFD = DFF * D_MODEL / 4;
            wconv_kernel<<<(nDD + 255) / 256, 256, 0, stream>>>(wq + (size_t)l * D_MODEL * D_MODEL, wqf, nDD);
            wconv_kernel<<<(nKD + 255) / 256, 256, 0, stream>>>(wk + (size_t)l * DKV * D_MODEL, wkf, nKD);
            wconv_kernel<<<(nKD + 255) / 256, 256, 0, stream>>>(wv + (size_t)l * DKV * D_MODEL, wvf, nKD);
            wconv_kernel<<<(nDD + 255) / 256, 256, 0, stream>>>(wo + (size_t)l * D_MODEL * D_MODEL, wof, nDD);
            wconv_kernel<<<(nFD + 255) / 256, 256, 0, stream>>>(wg + (size_t)l * DFF * D_MODEL, wgf, nFD);
            wconv_kernel<<<(nFD + 255) / 256, 256, 0, stream>>>(wu + (size_t)l * DFF * D_MODEL, wuf, nFD);
            wconv_kernel<<<(nFD + 255) / 256, 256, 0, stream>>>(wd + (size_t)l * D_MODEL * DFF, wdf, nFD);
        }

        rmsnorm_kernel<<<NTOK, 256, 0, stream>>>(X, g_attn + (size_t)l * D_MODEL, Hb);
        gemm_f16<0><<<dim3(32, 16), 256, 0, stream>>>(Hb, wqf, sq + (size_t)l * D_MODEL, Qb, NTOK, D_MODEL, D_MODEL);
        gemm_f16<0><<<dim3(32, 4),  256, 0, stream>>>(Hb, wkf, sk + (size_t)l * DKV, Kb, NTOK, DKV, D_MODEL);
        gemm_f16<0><<<dim3(32, 4),  256, 0, stream>>>(Hb, wvf, sv + (size_t)l * DKV, Vb, NTOK, DKV, D_MODEL);
        {
            int totq = NTOK * NH * 32;
            rope_f16_kernel<<<(totq + 255) / 256, 256, 0, stream>>>(Qb, NH, totq);
            int totk = NTOK * KVHEADS * 32;
            rope_f16_kernel<<<(totk + 255) / 256, 256, 0, stream>>>(Kb, KVHEADS, totk);
        }
        attn_kernel<<<1024, 256, 0, stream>>>(Qb, Kb, Vb, Ab);
        gemm_f16<1><<<dim3(32, 16), 256, 0, stream>>>(Ab, wof, so + (size_t)l * D_MODEL, X, NTOK, D_MODEL, D_MODEL);

        rmsnorm_kernel<<<NTOK, 256, 0, stream>>>(X, g_mlp + (size_t)l * D_MODEL, Hb);
        gemm_f16<0><<<dim3(32, 64), 256, 0, stream>>>(Hb, wuf, su + (size_t)l * DFF, Ub, NTOK, DFF, D_MODEL);
        gemm_f16<2><<<dim3(32, 64), 256, 0, stream>>>(Hb, wgf, sg + (size_t)l * DFF, Ub, NTOK, DFF, D_MODEL);
        gemm_f16<1><<<dim3(32, 16), 256, 0, stream>>>(Ub, wdf, sd + (size_t)l * D_MODEL, X, NTOK, D_MODEL, DFF);
    }

    final_norm_kernel<<<BATCH, 256, 0, stream>>>(X, g_fin, XF);
    lmhead_kernel<<<VOCAB / 64, 256, 0, stream>>>(XF, embed, out);
}

// Round 3
// 4219.854 us; speedup vs baseline: 1.8951x; 1.1062x over previous
//
#include <hip/hip_runtime.h>
#include <hip/hip_bf16.h>

#define D_MODEL 2048
#define NH 32
#define HDIM 64
#define KVHEADS 8
#define DKV 512
#define DFF 8192
#define SEQ 1024
#define BATCH 4
#define NTOK 4096
#define VOCAB 32000
#define NLAYER 4

typedef __attribute__((ext_vector_type(8))) _Float16 f16x8;
typedef __attribute__((ext_vector_type(4))) _Float16 f16x4;
typedef __attribute__((ext_vector_type(4))) float f32x4;

static __device__ __forceinline__ void gload16(const void* g, void* l){
    __builtin_amdgcn_global_load_lds(
        (const __attribute__((address_space(1))) unsigned int*)g,
        (__attribute__((address_space(3))) unsigned int*)l, 16, 0, 0);
}

// ---------------- embedding gather ----------------
__global__ __launch_bounds__(256)
void gather_kernel(const int* __restrict__ tok, const float* __restrict__ embed,
                   float* __restrict__ X)
{
    int row = blockIdx.x;
    int id = tok[row];
    const float4* s = (const float4*)(embed + (size_t)id * D_MODEL);
    float4* d = (float4*)(X + (size_t)row * D_MODEL);
    d[threadIdx.x]       = s[threadIdx.x];
    d[threadIdx.x + 256] = s[threadIdx.x + 256];
}

// ---------------- weight convert: int32 -> fp16 ----------------
__global__ __launch_bounds__(256)
void wconv_kernel(const int* __restrict__ W, _Float16* __restrict__ O, int n4)
{
    int i = blockIdx.x * 256 + threadIdx.x;
    if (i >= n4) return;
    int4 w = ((const int4*)W)[i];
    f16x4 o;
    o.x = (_Float16)(float)w.x; o.y = (_Float16)(float)w.y;
    o.z = (_Float16)(float)w.z; o.w = (_Float16)(float)w.w;
    ((f16x4*)O)[i] = o;
}

// ---------------- rmsnorm (fp32 in, fp16 out) ----------------
__global__ __launch_bounds__(256)
void rmsnorm_kernel(const float* __restrict__ X, const float* __restrict__ gamma,
                    _Float16* __restrict__ O)
{
    int row = blockIdx.x;
    const float* x = X + (size_t)row * D_MODEL;
    _Float16* o = O + (size_t)row * D_MODEL;
    int t = threadIdx.x;
    float4 v[2];
    float ss = 0.f;
#pragma unroll
    for (int i = 0; i < 2; i++){
        v[i] = *(const float4*)&x[(t + i*256)*4];
        ss += v[i].x*v[i].x + v[i].y*v[i].y + v[i].z*v[i].z + v[i].w*v[i].w;
    }
    for (int off = 32; off; off >>= 1) ss += __shfl_xor(ss, off, 64);
    __shared__ float red[4];
    __shared__ float invs;
    int lane = t & 63, wid = t >> 6;
    if (lane == 0) red[wid] = ss;
    __syncthreads();
    if (t == 0){
        float s = red[0] + red[1] + red[2] + red[3];
        invs = 1.0f / sqrtf(s / (float)D_MODEL + 1e-5f);
    }
    __syncthreads();
    float inv = invs;
#pragma unroll
    for (int i = 0; i < 2; i++){
        float4 g = *(const float4*)&gamma[(t + i*256)*4];
        f16x4 r;
        r.x = (_Float16)(v[i].x * inv * g.x); r.y = (_Float16)(v[i].y * inv * g.y);
        r.z = (_Float16)(v[i].z * inv * g.z); r.w = (_Float16)(v[i].w * inv * g.w);
        *(f16x4*)&o[(t + i*256)*4] = r;
    }
}

// final norm (fp32 out), last token per batch
__global__ __launch_bounds__(256)
void final_norm_kernel(const float* __restrict__ X, const float* __restrict__ gamma,
                       float* __restrict__ XF)
{
    int b = blockIdx.x;
    const float* x = X + ((size_t)b * SEQ + SEQ - 1) * D_MODEL;
    float* o = XF + (size_t)b * D_MODEL;
    int t = threadIdx.x;
    float4 v[2];
    float ss = 0.f;
#pragma unroll
    for (int i = 0; i < 2; i++){
        v[i] = *(const float4*)&x[(t + i*256)*4];
        ss += v[i].x*v[i].x + v[i].y*v[i].y + v[i].z*v[i].z + v[i].w*v[i].w;
    }
    for (int off = 32; off; off >>= 1) ss += __shfl_xor(ss, off, 64);
    __shared__ float red[4];
    __shared__ float invs;
    int lane = t & 63, wid = t >> 6;
    if (lane == 0) red[wid] = ss;
    __syncthreads();
    if (t == 0){
        float s = red[0] + red[1] + red[2] + red[3];
        invs = 1.0f / sqrtf(s / (float)D_MODEL + 1e-5f);
    }
    __syncthreads();
    float inv = invs;
#pragma unroll
    for (int i = 0; i < 2; i++){
        float4 g = *(const float4*)&gamma[(t + i*256)*4];
        float4 r;
        r.x = v[i].x * inv * g.x; r.y = v[i].y * inv * g.y;
        r.z = v[i].z * inv * g.z; r.w = v[i].w * inv * g.w;
        *(float4*)&o[(t + i*256)*4] = r;
    }
}

// ---------------- RoPE (fp16 in place, split-half) ----------------
__global__ __launch_bounds__(256)
void rope_f16_kernel(_Float16* __restrict__ buf, int nh, int total)
{
    int idx = blockIdx.x * 256 + threadIdx.x;
    if (idx >= total) return;
    int d = idx & 31;
    int head = (idx >> 5) % nh;
    int row = idx / (nh * 32);
    int pos = row & (SEQ - 1);
    float inv = powf(500000.0f, -(float)d * (1.0f / 32.0f));
    float ang = (float)pos * inv;
    float s, c;
    sincosf(ang, &s, &c);
    _Float16* p = buf + (size_t)row * (nh * HDIM) + head * HDIM + d;
    float x1 = (float)p[0], x2 = (float)p[32];
    p[0]  = (_Float16)(x1 * c - x2 * s);
    p[32] = (_Float16)(x1 * s + x2 * c);
}

// ================= 8-phase deep-pipelined GEMM =================
// C = A[M,K] @ W[N,K]^T * scale[N]
// BM=256, BN=128, BK=64, 512 threads (8 waves, 4x2), triple-buffered LDS.
// T2 swizzle: LDS slot ^= row&7, realized via inverse-swizzled global source
// (global_load_lds writes linearly) + swizzled ds_read.
// EPI: 0 = store f16; 1 = fp32 +=; 2 = silu(y)*C -> C (f16); 3 = qkv scatter
#define BM 256
#define BN 128
#define BK 64

template<int EPI>
__global__ __launch_bounds__(512, 1)
void gemm8(const _Float16* __restrict__ A, const _Float16* __restrict__ W,
           const float* __restrict__ sc0, const float* __restrict__ sc1,
           const float* __restrict__ sc2,
           void* __restrict__ C0, void* __restrict__ C1, void* __restrict__ C2,
           int MT, int NT, int N, int K)
{
    __shared__ __align__(16) _Float16 AS[3][BM * BK];
    __shared__ __align__(16) _Float16 BS[3][BN * BK];

    // bijective XCD swizzle (m204)
    int nwg = MT * NT;
    int flat = blockIdx.x;
    int q = nwg >> 3, r = nwg & 7;
    int xcd = flat & 7, lid = flat >> 3;
    int swz = (xcd < r ? xcd * (q + 1) : r * (q + 1) + (xcd - r) * q) + lid;
    int bm = swz % MT, bn = swz / MT;
    int m0 = bm * BM, n0 = bn * BN;

    const int t = threadIdx.x;
    const int lane = t & 63, wid = t >> 6;
    const int ln15 = lane & 15, lq = lane >> 4;
    const int wmM = (wid >> 1) * 64, wnN = (wid & 1) * 64;
    const int sw = ln15 & 7;                  // read-side swizzle

    // staging sources (inverse-swizzled global addresses)
    const _Float16* srcA[4]; const _Float16* srcB[2];
    int ldsA[4], ldsB[2];
#pragma unroll
    for (int ar = 0; ar < 4; ar++){
        int c = ar * 512 + wid * 64 + lane;
        int rr = c >> 3, ss = (c & 7) ^ (rr & 7);
        srcA[ar] = A + (size_t)(m0 + rr) * K + ss * 8;
        ldsA[ar] = (ar * 512 + wid * 64) * 8;
    }
#pragma unroll
    for (int br = 0; br < 2; br++){
        int c = br * 512 + wid * 64 + lane;
        int rr = c >> 3, ss = (c & 7) ^ (rr & 7);
        srcB[br] = W + (size_t)(n0 + rr) * K + ss * 8;
        ldsB[br] = (br * 512 + wid * 64) * 8;
    }

    // fragment LDS element offsets
    int aRow[4], bRow[4], slot[2];
#pragma unroll
    for (int i = 0; i < 4; i++){
        aRow[i] = (wmM + i * 16 + ln15) * BK;
        bRow[i] = (wnN + i * 16 + ln15) * BK;
    }
    slot[0] = ((0 + lq) ^ sw) * 8;
    slot[1] = ((4 + lq) ^ sw) * 8;

    f32x4 acc[4][4];
#pragma unroll
    for (int i = 0; i < 4; i++)
#pragma unroll
        for (int j = 0; j < 4; j++) acc[i][j] = (f32x4){0.f, 0.f, 0.f, 0.f};

    const int KT = K >> 6;     // K / 64, always >= 32 here

    // prologue: stage tiles 0 and 1
#pragma unroll
    for (int ar = 0; ar < 4; ar++) gload16(srcA[ar], &AS[0][ldsA[ar]]);
#pragma unroll
    for (int br = 0; br < 2; br++) gload16(srcB[br], &BS[0][ldsB[br]]);
#pragma unroll
    for (int ar = 0; ar < 4; ar++) gload16(srcA[ar] + BK, &AS[1][ldsA[ar]]);
#pragma unroll
    for (int br = 0; br < 2; br++) gload16(srcB[br] + BK, &BS[1][ldsB[br]]);
    asm volatile("s_waitcnt vmcnt(6)" ::: "memory");
    __builtin_amdgcn_s_barrier();
    __builtin_amdgcn_sched_barrier(0);

#define MFMA16(d, x, y) d = __builtin_amdgcn_mfma_f32_16x16x32_f16(x, y, d, 0, 0, 0)

    int cur = 0;
    for (int kt = 0; kt < KT; ++kt){
        const _Float16* Ab_ = &AS[cur][0];
        const _Float16* Bb_ = &BS[cur][0];
        const int kt2 = kt + 2;
        const bool st = kt2 < KT;
        const int nb = (cur >= 1) ? cur - 1 : cur + 2;
        const size_t koff = (size_t)kt2 * BK;

        // ---- P1: read a0*,a1*,b0*,b1* ; stage A rounds 0,1
        f16x8 a00 = *(const f16x8*)&Ab_[aRow[0] + slot[0]];
        f16x8 a01 = *(const f16x8*)&Ab_[aRow[0] + slot[1]];
        f16x8 a10 = *(const f16x8*)&Ab_[aRow[1] + slot[0]];
        f16x8 a11 = *(const f16x8*)&Ab_[aRow[1] + slot[1]];
        f16x8 b00 = *(const f16x8*)&Bb_[bRow[0] + slot[0]];
        f16x8 b01 = *(const f16x8*)&Bb_[bRow[0] + slot[1]];
        f16x8 b10 = *(const f16x8*)&Bb_[bRow[1] + slot[0]];
        f16x8 b11 = *(const f16x8*)&Bb_[bRow[1] + slot[1]];
        if (st){
            gload16(srcA[0] + koff, &AS[nb][ldsA[0]]);
            gload16(srcA[1] + koff, &AS[nb][ldsA[1]]);
        }
        __builtin_amdgcn_s_barrier();
        asm volatile("s_waitcnt lgkmcnt(0)" ::: "memory");
        __builtin_amdgcn_sched_barrier(0);
        __builtin_amdgcn_s_setprio(1);
        MFMA16(acc[0][0], a00, b00); MFMA16(acc[0][0], a01, b01);
        MFMA16(acc[0][1], a00, b10); MFMA16(acc[0][1], a01, b11);
        MFMA16(acc[1][0], a10, b00); MFMA16(acc[1][0], a11, b01);
        MFMA16(acc[1][1], a10, b10); MFMA16(acc[1][1], a11, b11);
        __builtin_amdgcn_s_setprio(0);
        __builtin_amdgcn_s_barrier();

        // ---- P2: read a2*,a3* ; stage A rounds 2,3
        f16x8 a20 = *(const f16x8*)&Ab_[aRow[2] + slot[0]];
        f16x8 a21 = *(const f16x8*)&Ab_[aRow[2] + slot[1]];
        f16x8 a30 = *(const f16x8*)&Ab_[aRow[3] + slot[0]];
        f16x8 a31 = *(const f16x8*)&Ab_[aRow[3] + slot[1]];
        if (st){
            gload16(srcA[2] + koff, &AS[nb][ldsA[2]]);
            gload16(srcA[3] + koff, &AS[nb][ldsA[3]]);
        }
        __builtin_amdgcn_s_barrier();
        asm volatile("s_waitcnt lgkmcnt(0)" ::: "memory");
        __builtin_amdgcn_sched_barrier(0);
        __builtin_amdgcn_s_setprio(1);
        MFMA16(acc[2][0], a20, b00); MFMA16(acc[2][0], a21, b01);
        MFMA16(acc[2][1], a20, b10); MFMA16(acc[2][1], a21, b11);
        MFMA16(acc[3][0], a30, b00); MFMA16(acc[3][0], a31, b01);
        MFMA16(acc[3][1], a30, b10); MFMA16(acc[3][1], a31, b11);
        __builtin_amdgcn_s_setprio(0);
        __builtin_amdgcn_s_barrier();

        // ---- P3: read b2*,b3* ; stage B rounds 0,1
        f16x8 b20 = *(const f16x8*)&Bb_[bRow[2] + slot[0]];
        f16x8 b21 = *(const f16x8*)&Bb_[bRow[2] + slot[1]];
        f16x8 b30 = *(const f16x8*)&Bb_[bRow[3] + slot[0]];
        f16x8 b31 = *(const f16x8*)&Bb_[bRow[3] + slot[1]];
        if (st){
            gload16(srcB[0] + koff, &BS[nb][ldsB[0]]);
            gload16(srcB[1] + koff, &BS[nb][ldsB[1]]);
        }
        __builtin_amdgcn_s_barrier();
        asm volatile("s_waitcnt lgkmcnt(0)" ::: "memory");
        __builtin_amdgcn_sched_barrier(0);
        __builtin_amdgcn_s_setprio(1);
        MFMA16(acc[0][2], a00, b20); MFMA16(acc[0][2], a01, b21);
        MFMA16(acc[0][3], a00, b30); MFMA16(acc[0][3], a01, b31);
        MFMA16(acc[1][2], a10, b20); MFMA16(acc[1][2], a11, b21);
        MFMA16(acc[1][3], a10, b30); MFMA16(acc[1][3], a11, b31);
        __builtin_amdgcn_s_setprio(0);
        __builtin_amdgcn_s_barrier();

        // ---- P4: remaining quadrant; counted vmcnt + barrier
        __builtin_amdgcn_s_setprio(1);
        MFMA16(acc[2][2], a20, b20); MFMA16(acc[2][2], a21, b21);
        MFMA16(acc[2][3], a20, b30); MFMA16(acc[2][3], a21, b31);
        MFMA16(acc[3][2], a30, b20); MFMA16(acc[3][2], a31, b21);
        MFMA16(acc[3][3], a30, b30); MFMA16(acc[3][3], a31, b31);
        __builtin_amdgcn_s_setprio(0);
        if (kt + 1 < KT){
            if (st) asm volatile("s_waitcnt vmcnt(6)" ::: "memory");
            else    asm volatile("s_waitcnt vmcnt(0)" ::: "memory");
            __builtin_amdgcn_s_barrier();
            __builtin_amdgcn_sched_barrier(0);
        }
        cur = (cur == 2) ? 0 : cur + 1;
    }
#undef MFMA16

    // ---- epilogue ----
    if (EPI == 3){
        const float* sp; _Float16* dp; int nloc, nstr;
        if (n0 < 2048)      { sp = sc0; dp = (_Float16*)C0; nloc = n0;        nstr = 2048; }
        else if (n0 < 2560) { sp = sc1; dp = (_Float16*)C1; nloc = n0 - 2048; nstr = 512; }
        else                { sp = sc2; dp = (_Float16*)C2; nloc = n0 - 2560; nstr = 512; }
#pragma unroll
        for (int mf = 0; mf < 4; mf++){
            int rowb = m0 + wmM + mf * 16 + lq * 4;
#pragma unroll
            for (int nf = 0; nf < 4; nf++){
                int colg = wnN + nf * 16 + ln15;
                float sc = sp[nloc + colg];
#pragma unroll
                for (int rr2 = 0; rr2 < 4; rr2++)
                    dp[(size_t)(rowb + rr2) * nstr + nloc + colg] =
                        (_Float16)(acc[mf][nf][rr2] * sc);
            }
        }
    } else {
#pragma unroll
        for (int mf = 0; mf < 4; mf++){
            int rowb = m0 + wmM + mf * 16 + lq * 4;
#pragma unroll
            for (int nf = 0; nf < 4; nf++){
                int colg = n0 + wnN + nf * 16 + ln15;
                float sc = sc0[colg];
#pragma unroll
                for (int rr2 = 0; rr2 < 4; rr2++){
                    size_t idx = (size_t)(rowb + rr2) * N + colg;
                    float val = acc[mf][nf][rr2] * sc;
                    if (EPI == 0){
                        ((_Float16*)C0)[idx] = (_Float16)val;
                    } else if (EPI == 1){
                        ((float*)C0)[idx] += val;
                    } else {
                        _Float16* C = (_Float16*)C0;
                        float uv = (float)C[idx];
                        float sig = 1.0f / (1.0f + expf(-val));
                        C[idx] = (_Float16)(val * sig * uv);
                    }
                }
            }
        }
    }
}

// ---------------- flash attention (causal, GQA 4:1, fp16) ----------------
__global__ __launch_bounds__(256)
void attn_kernel(const _Float16* __restrict__ Qb, const _Float16* __restrict__ Kb,
                 const _Float16* __restrict__ Vb, _Float16* __restrict__ Ob)
{
    int bid = blockIdx.x;
    int qt = bid & 7, h = (bid >> 3) & 31, b = bid >> 8;
    int kvh = h >> 2;
    int q0 = qt * 128;
    int t = threadIdx.x, lane = t & 63, wid = t >> 6;
    int ln15 = lane & 15, lq = lane >> 4;

    __shared__ __align__(16) _Float16 Ksm[64 * 72];
    __shared__ __align__(16) _Float16 Vt[64 * 72];
    __shared__ __align__(16) _Float16 Pl[128 * 72];

    f16x8 qf[2][2];
    int qrow_g = b * SEQ + q0 + wid * 32;
#pragma unroll
    for (int mf = 0; mf < 2; mf++)
#pragma unroll
        for (int dc = 0; dc < 2; dc++)
            qf[mf][dc] = *(const f16x8*)(Qb + (size_t)(qrow_g + mf * 16 + ln15) * D_MODEL
                                         + h * HDIM + dc * 32 + lq * 8);

    f32x4 outv[2][4];
#pragma unroll
    for (int i = 0; i < 2; i++)
#pragma unroll
        for (int j = 0; j < 4; j++) outv[i][j] = (f32x4){0.f, 0.f, 0.f, 0.f};
    float mrun[2][4], lrun[2][4];
#pragma unroll
    for (int i = 0; i < 2; i++)
#pragma unroll
        for (int r = 0; r < 4; r++){ mrun[i][r] = -1e30f; lrun[i][r] = 0.f; }

    int ntile = (q0 + 128) >> 6;
    for (int kt = 0; kt < ntile; kt++){
        f16x8 k8[2], v8[2];
#pragma unroll
        for (int i = 0; i < 2; i++){
            int f = t + i * 256;
            int row = f >> 3, c8 = f & 7;
            size_t base = (size_t)(b * SEQ + kt * 64 + row) * DKV + kvh * HDIM + c8 * 8;
            k8[i] = *(const f16x8*)&Kb[base];
            v8[i] = *(const f16x8*)&Vb[base];
        }
        __syncthreads();
#pragma unroll
        for (int i = 0; i < 2; i++){
            int f = t + i * 256;
            int row = f >> 3, c8 = f & 7;
            *(f16x8*)&Ksm[row * 72 + c8 * 8] = k8[i];
#pragma unroll
            for (int j = 0; j < 8; j++)
                Vt[(c8 * 8 + j) * 72 + row] = v8[i][j];
        }
        __syncthreads();

#pragma unroll
        for (int mf = 0; mf < 2; mf++){
            f32x4 sa[4];
#pragma unroll
            for (int kvf = 0; kvf < 4; kvf++) sa[kvf] = (f32x4){0.f, 0.f, 0.f, 0.f};
#pragma unroll
            for (int kvf = 0; kvf < 4; kvf++)
#pragma unroll
                for (int dc = 0; dc < 2; dc++){
                    f16x8 kb = *(const f16x8*)&Ksm[(kvf * 16 + ln15) * 72 + dc * 32 + lq * 8];
                    sa[kvf] = __builtin_amdgcn_mfma_f32_16x16x32_f16(qf[mf][dc], kb, sa[kvf], 0, 0, 0);
                }
            int qbase = q0 + wid * 32 + mf * 16 + lq * 4;
            float rowmax[4] = {-1e30f, -1e30f, -1e30f, -1e30f};
#pragma unroll
            for (int kvf = 0; kvf < 4; kvf++){
                int kva = kt * 64 + kvf * 16 + ln15;
#pragma unroll
                for (int r = 0; r < 4; r++){
                    float sv = sa[kvf][r] * 0.125f;
                    if (kva > qbase + r) sv = -1e9f;
                    sa[kvf][r] = sv;
                    rowmax[r] = fmaxf(rowmax[r], sv);
                }
            }
#pragma unroll
            for (int r = 0; r < 4; r++){
                rowmax[r] = fmaxf(rowmax[r], __shfl_xor(rowmax[r], 1, 64));
                rowmax[r] = fmaxf(rowmax[r], __shfl_xor(rowmax[r], 2, 64));
                rowmax[r] = fmaxf(rowmax[r], __shfl_xor(rowmax[r], 4, 64));
                rowmax[r] = fmaxf(rowmax[r], __shfl_xor(rowmax[r], 8, 64));
            }
            float scl[4], rsum[4];
#pragma unroll
            for (int r = 0; r < 4; r++){
                float mo = mrun[mf][r];
                float mn = fmaxf(mo, rowmax[r]);
                scl[r] = expf(mo - mn);
                mrun[mf][r] = mn;
                rsum[r] = 0.f;
            }
#pragma unroll
            for (int kvf = 0; kvf < 4; kvf++)
#pragma unroll
                for (int r = 0; r < 4; r++){
                    float p = expf(sa[kvf][r] - mrun[mf][r]);
                    sa[kvf][r] = p;
                    rsum[r] += p;
                }
#pragma unroll
            for (int r = 0; r < 4; r++){
                rsum[r] += __shfl_xor(rsum[r], 1, 64);
                rsum[r] += __shfl_xor(rsum[r], 2, 64);
                rsum[r] += __shfl_xor(rsum[r], 4, 64);
                rsum[r] += __shfl_xor(rsum[r], 8, 64);
                lrun[mf][r] = lrun[mf][r] * scl[r] + rsum[r];
            }
#pragma unroll
            for (int dfr = 0; dfr < 4; dfr++)
#pragma unroll
                for (int r = 0; r < 4; r++) outv[mf][dfr][r] *= scl[r];
#pragma unroll
            for (int kvf = 0; kvf < 4; kvf++)
#pragma unroll
                for (int r = 0; r < 4; r++)
                    Pl[(wid * 32 + mf * 16 + lq * 4 + r) * 72 + kvf * 16 + ln15] = (_Float16)sa[kvf][r];
        }
        __syncthreads();

#pragma unroll
        for (int mf = 0; mf < 2; mf++)
#pragma unroll
            for (int kc = 0; kc < 2; kc++){
                f16x8 pa = *(const f16x8*)&Pl[(wid * 32 + mf * 16 + ln15) * 72 + kc * 32 + lq * 8];
#pragma unroll
                for (int dfr = 0; dfr < 4; dfr++){
                    f16x8 vb = *(const f16x8*)&Vt[(dfr * 16 + ln15) * 72 + kc * 32 + lq * 8];
                    outv[mf][dfr] = __builtin_amdgcn_mfma_f32_16x16x32_f16(pa, vb, outv[mf][dfr], 0, 0, 0);
                }
            }
    }

#pragma unroll
    for (int mf = 0; mf < 2; mf++)
#pragma unroll
        for (int dfr = 0; dfr < 4; dfr++)
#pragma unroll
            for (int r = 0; r < 4; r++){
                float val = outv[mf][dfr][r] / lrun[mf][r];
                size_t row = (size_t)(b * SEQ + q0 + wid * 32 + mf * 16 + lq * 4 + r);
                Ob[row * D_MODEL + h * HDIM + dfr * 16 + ln15] = (_Float16)val;
            }
}

// ---------------- LM head: out[b][v] = xf[b] . embed[v] ----------------
__global__ __launch_bounds__(256)
void lmhead_kernel(const float* __restrict__ XF, const float* __restrict__ embed,
                   float* __restrict__ out)
{
    __shared__ float xl[4 * D_MODEL];
    int t = threadIdx.x;
#pragma unroll
    for (int i = 0; i < 8; i++){
        int f = t + i * 256;
        ((float4*)xl)[f] = ((const float4*)XF)[f];
    }
    __syncthreads();
    int lane = t & 63, wid = t >> 6;
    for (int rr = 0; rr < 16; rr++){
        int vrow = blockIdx.x * 64 + wid * 16 + rr;
        const float4* er = (const float4*)(embed + (size_t)vrow * D_MODEL);
        float acc[4] = {0.f, 0.f, 0.f, 0.f};
        for (int j = 0; j < 8; j++){
            float4 e = er[lane + 64 * j];
#pragma unroll
            for (int b = 0; b < 4; b++){
                float4 xv = ((float4*)xl)[b * 512 + lane + 64 * j];
                acc[b] += e.x * xv.x + e.y * xv.y + e.z * xv.z + e.w * xv.w;
            }
        }
#pragma unroll
        for (int b = 0; b < 4; b++)
            for (int off = 32; off; off >>= 1) acc[b] += __shfl_xor(acc[b], off, 64);
        if (lane == 0){
#pragma unroll
            for (int b = 0; b < 4; b++)
                out[(size_t)b * VOCAB + vrow] = acc[b];
        }
    }
}

extern "C" void kernel_launch(void* const* d_in, const int* in_sizes, int n_in,
                              void* d_out, int out_size, void* d_ws, size_t ws_size,
                              hipStream_t stream)
{
    const int*   tok   = (const int*)d_in[0];
    const float* embed = (const float*)d_in[1];
    const float* g_attn = (const float*)d_in[2];
    const float* g_mlp  = (const float*)d_in[3];
    const float* g_fin  = (const float*)d_in[4];
    const int*   wq = (const int*)d_in[5];  const float* sq = (const float*)d_in[6];
    const int*   wk = (const int*)d_in[7];  const float* sk = (const float*)d_in[8];
    const int*   wv = (const int*)d_in[9];  const float* sv = (const float*)d_in[10];
    const int*   wo = (const int*)d_in[11]; const float* so = (const float*)d_in[12];
    const int*   wg = (const int*)d_in[13]; const float* sg = (const float*)d_in[14];
    const int*   wu = (const int*)d_in[15]; const float* su = (const float*)d_in[16];
    const int*   wd = (const int*)d_in[17]; const float* sd = (const float*)d_in[18];
    float* out = (float*)d_out;

    char* p = (char*)d_ws;
    _Float16* Wf = (_Float16*)p;  p += (size_t)60817408 * 2;   // per-layer fp16 weights
    float*    X  = (float*)p;     p += (size_t)NTOK * D_MODEL * 4;
    _Float16* Hb = (_Float16*)p;  p += (size_t)NTOK * D_MODEL * 2;
    _Float16* Qb = (_Float16*)p;  p += (size_t)NTOK * D_MODEL * 2;
    _Float16* Kb = (_Float16*)p;  p += (size_t)NTOK * DKV * 2;
    _Float16* Vb = (_Float16*)p;  p += (size_t)NTOK * DKV * 2;
    _Float16* Ab = (_Float16*)p;  p += (size_t)NTOK * D_MODEL * 2;
    _Float16* Ub = (_Float16*)p;  p += (size_t)NTOK * DFF * 2;
    float*    XF = (float*)p;     p += (size_t)BATCH * D_MODEL * 4;

    _Float16* wqf = Wf;                                   // [2048 x 2048]
    _Float16* wkf = wqf + (size_t)D_MODEL * D_MODEL;      // [512 x 2048]
    _Float16* wvf = wkf + (size_t)DKV * D_MODEL;          // [512 x 2048]
    _Float16* wof = wvf + (size_t)DKV * D_MODEL;
    _Float16* wgf = wof + (size_t)D_MODEL * D_MODEL;
    _Float16* wuf = wgf + (size_t)DFF * D_MODEL;
    _Float16* wdf = wuf + (size_t)DFF * D_MODEL;

    gather_kernel<<<NTOK, 256, 0, stream>>>(tok, embed, X);

    for (int l = 0; l < NLAYER; l++){
        {
            const int nDD = D_MODEL * D_MODEL / 4, nKD = DKV * D_MODEL / 4, nFD = DFF * D_MODEL / 4;
            wconv_kernel<<<(nDD + 255) / 256, 256, 0, stream>>>(wq + (size_t)l * D_MODEL * D_MODEL, wqf, nDD);
            wconv_kernel<<<(nKD + 255) / 256, 256, 0, stream>>>(wk + (size_t)l * DKV * D_MODEL, wkf, nKD);
            wconv_kernel<<<(nKD + 255) / 256, 256, 0, stream>>>(wv + (size_t)l * DKV * D_MODEL, wvf, nKD);
            wconv_kernel<<<(nDD + 255) / 256, 256, 0, stream>>>(wo + (size_t)l * D_MODEL * D_MODEL, wof, nDD);
            wconv_kernel<<<(nFD + 255) / 256, 256, 0, stream>>>(wg + (size_t)l * DFF * D_MODEL, wgf, nFD);
            wconv_kernel<<<(nFD + 255) / 256, 256, 0, stream>>>(wu + (size_t)l * DFF * D_MODEL, wuf, nFD);
            wconv_kernel<<<(nFD + 255) / 256, 256, 0, stream>>>(wd + (size_t)l * D_MODEL * DFF, wdf, nFD);
        }

        rmsnorm_kernel<<<NTOK, 256, 0, stream>>>(X, g_attn + (size_t)l * D_MODEL, Hb);
        // fused QKV: N = 3072 (q|k|v rows contiguous in Wf)
        gemm8<3><<<16 * 24, 512, 0, stream>>>(Hb, wqf,
            sq + (size_t)l * D_MODEL, sk + (size_t)l * DKV, sv + (size_t)l * DKV,
            Qb, Kb, Vb, 16, 24, 3072, D_MODEL);
        {
            int totq = NTOK * NH * 32;
            rope_f16_kernel<<<(totq + 255) / 256, 256, 0, stream>>>(Qb, NH, totq);
            int totk = NTOK * KVHEADS * 32;
            rope_f16_kernel<<<(totk + 255) / 256, 256, 0, stream>>>(Kb, KVHEADS, totk);
        }
        attn_kernel<<<1024, 256, 0, stream>>>(Qb, Kb, Vb, Ab);
        gemm8<1><<<16 * 16, 512, 0, stream>>>(Ab, wof,
            so + (size_t)l * D_MODEL, nullptr, nullptr,
            X, nullptr, nullptr, 16, 16, D_MODEL, D_MODEL);

        rmsnorm_kernel<<<NTOK, 256, 0, stream>>>(X, g_mlp + (size_t)l * D_MODEL, Hb);
        gemm8<0><<<16 * 64, 512, 0, stream>>>(Hb, wuf,
            su + (size_t)l * DFF, nullptr, nullptr,
            Ub, nullptr, nullptr, 16, 64, DFF, D_MODEL);
        gemm8<2><<<16 * 64, 512, 0, stream>>>(Hb, wgf,
            sg + (size_t)l * DFF, nullptr, nullptr,
            Ub, nullptr, nullptr, 16, 64, DFF, D_MODEL);
        gemm8<1><<<16 * 16, 512, 0, stream>>>(Ub, wdf,
            sd + (size_t)l * D_MODEL, nullptr, nullptr,
            X, nullptr, nullptr, 16, 16, D_MODEL, DFF);
    }

    final_norm_kernel<<<BATCH, 256, 0, stream>>>(X, g_fin, XF);
    lmhead_kernel<<<VOCAB / 64, 256, 0, stream>>>(XF, embed, out);
}